// Round 10
// baseline (258.547 us; speedup 1.0000x reference)
//
#include <hip/hip_runtime.h>
#include <math.h>

#define BB 16
#define LL 128
#define D_IN 8
#define HH 128
#define NLAYER 2
#define FUT 12
#define MDIM 2

typedef __attribute__((ext_vector_type(8))) __bf16 bf16x8;
typedef __attribute__((ext_vector_type(8))) short short8v;
typedef __attribute__((ext_vector_type(4))) float f32x4;

#define MFMA_B16(A, B, C) __builtin_amdgcn_mfma_f32_16x16x32_bf16(A, B, C, 0, 0, 0)

static __device__ __forceinline__ short f2bf(float f) {
    union { float f; unsigned u; } v; v.f = f;
    unsigned r = v.u + 0x7FFFu + ((v.u >> 16) & 1u);
    return (short)(r >> 16);
}

static __device__ __forceinline__ float tanh_fast(float x) {
    float e = __expf(2.f * x);
    return 1.f - 2.f / (e + 1.f);
}

// ---------------- merged prep: ts+h0 | compose (split-K) | weight transpose ----------------
__global__ __launch_bounds__(256) void k_prep(const float* __restrict__ hist, const float* __restrict__ mask,
                                              const float* __restrict__ Wp, const float* __restrict__ bp,
                                              const float* __restrict__ We2, const float* __restrict__ be2,
                                              const float* __restrict__ Wa1, const float* __restrict__ ba1,
                                              const float* __restrict__ Wm1, const float* __restrict__ bm1,
                                              const float* __restrict__ Wo1, const float* __restrict__ Wm2,
                                              const float* __restrict__ Wo2,
                                              float* __restrict__ ts, float* __restrict__ h,
                                              short* __restrict__ AmT, short* __restrict__ MmT,
                                              float* __restrict__ ca, float* __restrict__ cm,
                                              short* __restrict__ WT4, short* __restrict__ WT3) {
    __shared__ float row[HH];
    __shared__ float pa[256], pm[256];
    const int bid = blockIdx.x, tid = threadIdx.x;
    const int NC = NLAYER * (HH + 1);
    if (bid < BB) {
        int b = bid;
        if (tid < LL) row[tid] = fmaxf(hist[(b * LL + tid) * D_IN + 5], 0.f);
        __syncthreads();
        for (int d = 1; d < LL; d <<= 1) {
            float add = (tid < LL && tid >= d) ? row[tid - d] : 0.f;
            __syncthreads();
            if (tid < LL) row[tid] += add;
            __syncthreads();
        }
        if (tid < LL) ts[b * LL + tid] = row[tid];
        int k = tid & (HH - 1);
        float wp_r[D_IN];
#pragma unroll
        for (int f = 0; f < D_IN; f++) wp_r[f] = Wp[f * HH + k];
        float bpk = bp[k];
        int jbase = tid >> 7;
        for (int e = 0; e < 64; e++) {
            int j = e * 2 + jbase;
            int bj = b * LL + j;
            const float* hr = hist + (size_t)bj * D_IN;
            float acc = bpk;
#pragma unroll
            for (int f = 0; f < D_IN; f++) acc += hr[f] * wp_r[f];
            h[(size_t)bj * HH + k] = acc * (mask[bj] > 0.f ? 1.f : 0.f);
        }
    } else if (bid < BB + NC) {
        int cb = bid - BB;
        int l = cb / (HH + 1);
        int p = cb % (HH + 1);
        const float* WaE = Wa1 + (size_t)(l * 3 * HH + 2 * HH) * HH;
        const float* WmE = Wm1 + (size_t)(l * 2 * HH + HH) * HH;
        int q = tid & 127, kh = tid >> 7;
        if (tid < HH) row[tid] = (p < HH) ? We2[(size_t)(l * HH + p) * HH + tid] : be2[l * HH + tid];
        __syncthreads();
        float a = 0.f, m = 0.f;
        int kbase = kh * 64;
#pragma unroll 4
        for (int k = 0; k < 64; k++) {
            float w = row[kbase + k];
            a += w * WaE[(size_t)(kbase + k) * HH + q];
            m += w * WmE[(size_t)(kbase + k) * HH + q];
        }
        pa[tid] = a;
        pm[tid] = m;
        __syncthreads();
        if (tid < HH) {
            a = pa[tid] + pa[128 + tid];
            m = pm[tid] + pm[128 + tid];
            if (p < HH) {
                AmT[(size_t)l * HH * HH + tid * HH + p] = f2bf(a);
                MmT[(size_t)l * HH * HH + tid * HH + p] = f2bf(m);
            } else {
                ca[l * HH + tid] = a + ba1[l * HH + tid];
                cm[l * HH + tid] = m + bm1[l * HH + tid];
            }
        }
    } else {
        int m7 = bid - BB - NC;
        int l = m7 / 7, m = m7 % 7;
        const float* src;
        switch (m) {
            case 0: src = Wa1 + (size_t)(l * 3 * HH) * HH; break;
            case 1: src = Wa1 + (size_t)(l * 3 * HH + HH) * HH; break;
            case 2: src = Wm1 + (size_t)(l * 2 * HH) * HH; break;
            case 3: src = Wo1 + (size_t)(l * 2 * HH) * HH; break;
            case 4: src = Wm2 + (size_t)l * HH * HH; break;
            case 5: src = Wo1 + (size_t)(l * 2 * HH + HH) * HH; break;
            default: src = Wo2 + (size_t)l * HH * HH; break;
        }
        short* dst = (m < 4) ? (WT4 + (size_t)(l * 4 + m) * HH * HH)
                             : (WT3 + (size_t)(l * 3 + (m - 4)) * HH * HH);
        // coalesced READS (contiguous src rows per lane), scattered 2B writes
#pragma unroll 4
        for (int e = 0; e < 64; e++) {
            int idx = e * 256 + tid;
            int kk = idx >> 7;       // src row
            int c = idx & 127;       // src col, contiguous per lane -> coalesced read
            dst[c * HH + kk] = f2bf(src[(size_t)kk * HH + c]);
        }
    }
}

// ---------------- batched pre-projections, 256 blocks: base_a, da, base_m, oa ----------------
__global__ __launch_bounds__(256) void k_pre(const float* __restrict__ h, const short* __restrict__ WT4,
                                             const float* __restrict__ ca, const float* __restrict__ cm,
                                             float* __restrict__ base_a, float* __restrict__ da,
                                             float* __restrict__ base_m, float* __restrict__ oa, int l) {
    __shared__ __align__(16) short hA[16][136];
    const int tid = threadIdx.x, lane = tid & 63, wv = tid >> 6;
    const int lo = lane & 15, g4 = lane >> 4;
    const int rt = blockIdx.x >> 1, half = blockIdx.x & 1;
    const int r0 = rt * 16;
    {
        int row = tid >> 4, cc = (tid & 15) * 8;
        const float* hr = h + (size_t)(r0 + row) * HH + cc;
        short8v pk;
#pragma unroll
        for (int e = 0; e < 8; e++) pk[e] = f2bf(hr[e]);
        *(short8v*)&hA[row][cc] = pk;
    }
    __syncthreads();
    bf16x8 af[4];
#pragma unroll
    for (int ks = 0; ks < 4; ks++)
        af[ks] = *(const bf16x8*)&hA[lo][ks * 32 + g4 * 8];
    const int mat = half * 2 + (wv & 1);
    const int ctbase = (wv >> 1) * 4;
    const short* Wl = WT4 + (size_t)(l * 4 + mat) * HH * HH;
    float* dst;
    const float* bias = nullptr;
    if (mat == 0) { dst = base_a; bias = ca + l * HH; }
    else if (mat == 1) dst = da;
    else if (mat == 2) { dst = base_m; bias = cm + l * HH; }
    else dst = oa;
#pragma unroll
    for (int cc2 = 0; cc2 < 4; cc2++) {
        int col = (ctbase + cc2) * 16 + lo;
        bf16x8 Bf[4];
#pragma unroll
        for (int ks = 0; ks < 4; ks++)
            Bf[ks] = *(const bf16x8*)(Wl + (size_t)col * HH + ks * 32 + g4 * 8);
        f32x4 acc = (f32x4){0.f, 0.f, 0.f, 0.f};
#pragma unroll
        for (int ks = 0; ks < 4; ks++) acc = MFMA_B16(af[ks], Bf[ks], acc);
        float bv = bias ? bias[col] : 0.f;
#pragma unroll
        for (int rg = 0; rg < 4; rg++)
            dst[(size_t)(r0 + g4 * 4 + rg) * HH + col] = acc[rg] + bv;
    }
}

// ---------------- attention core: 512 threads, C[k][j], packed-fp32 t-compute ----------------
__global__ __launch_bounds__(512) void k_attn(
    const float* __restrict__ hist, const float* __restrict__ mask, const float* __restrict__ ts,
    const float* __restrict__ base_a_g, const float* __restrict__ base_m_g, const float* __restrict__ da,
    const short* __restrict__ AmT, const short* __restrict__ MmT,
    const float* __restrict__ wa2, const float* __restrict__ ba2,
    const float* __restrict__ We1, const float* __restrict__ be1,
    float* __restrict__ v_out, int l) {
    __shared__ __align__(16) short t_lds[LL][LL];    // 32768 B, XOR-swizzled
    __shared__ __align__(16) float bufA[1024];       // staging -> att partials [8][128]
    __shared__ float w_lds[LL];
    __shared__ float val_s[LL];                      // total 37888 B

    const int tid = threadIdx.x;
    const int lane = tid & 63;
    const int wv = tid >> 6;            // wave owns k rows [wv*16, wv*16+16)
    const int lo = lane & 15, g4 = lane >> 4;
    const int kq = wv * 16 + g4 * 4;    // this lane's k-quad base (C rows)
    const int bi = blockIdx.x, b = bi >> 7, i = bi & (LL - 1);

    // per-lane k-quad params (broadcast f32x4 loads)
    const f32x4 ba4 = *(const f32x4*)(base_a_g + (size_t)bi * HH + kq);
    const f32x4 bm4 = *(const f32x4*)(base_m_g + (size_t)bi * HH + kq);
    const f32x4 wa4 = *(const f32x4*)(wa2 + l * HH + kq);
    const float ba2l = ba2[l];

    // A-frags from AmT (rows k = wv*16+lo)
    bf16x8 Bf[4];
#pragma unroll
    for (int ks = 0; ks < 4; ks++)
        Bf[ks] = *(const bf16x8*)(AmT + (size_t)l * HH * HH + (size_t)(wv * 16 + lo) * HH + ks * 32 + g4 * 8);

    // stage: [0..127]=Wa(dist) [128..255]=Wb(dt) [256..383]=base0(be) [384..511]=base1(be+Wc) [512..639]=Wd
    {
        const float* We1l = We1 + l * 4 * HH;
        const float* be1l = be1 + l * HH;
        if (tid < 256) bufA[tid] = We1l[tid];
        else if (tid < 384) bufA[tid] = be1l[tid - 256];
        else bufA[tid] = be1l[tid - 384] + We1l[256 + (tid - 384)];
        if (tid < 128) {
            bufA[512 + tid] = We1l[384 + tid];
            val_s[tid] = mask[b * LL + tid];
        }
    }
    __syncthreads();

    // t = relu(ea*Wa + eb*Wb + base_sel (+Wd if diag)) -> swizzled LDS bf16 (packed fp32 + pk cvt)
    {
        int jj = tid & (LL - 1);
        int q4 = tid >> 7;  // 0..3
        const float* hri = hist + (size_t)(b * LL + i) * D_IN;
        const float* hrj = hist + (size_t)(b * LL + jj) * D_IN;
        float dlat = hri[0] - hrj[0], dlon = hri[1] - hrj[1];
        float ea = sqrtf(dlat * dlat + dlon * dlon + 1e-8f);
        float eb = fabsf(ts[b * LL + i] - ts[b * LL + jj]) * (1.f / 300.f);
        const float* basep = bufA + ((hri[6] == hrj[6]) ? 384 : 256);
        char* trow = (char*)t_lds + jj * 256;
        int swz = (jj & 7) << 4;
        bool diag = (jj == i);
#pragma unroll
        for (int pass = 0; pass < 4; pass++) {
            int r0c = (q4 + pass * 4) * 8;
            f32x4 v0, v1;
            {
                f32x4 wa0 = *(const f32x4*)&bufA[r0c];
                f32x4 wb0 = *(const f32x4*)&bufA[128 + r0c];
                f32x4 bs0 = *(const f32x4*)&basep[r0c];
                v0 = wa0 * ea + wb0 * eb + bs0;
                f32x4 wa1 = *(const f32x4*)&bufA[r0c + 4];
                f32x4 wb1 = *(const f32x4*)&bufA[128 + r0c + 4];
                f32x4 bs1 = *(const f32x4*)&basep[r0c + 4];
                v1 = wa1 * ea + wb1 * eb + bs1;
            }
            if (diag) {
                v0 += *(const f32x4*)&bufA[512 + r0c];
                v1 += *(const f32x4*)&bufA[512 + r0c + 4];
            }
            bf16x8 pkb;
#pragma unroll
            for (int e = 0; e < 4; e++) {
                pkb[e] = (__bf16)fmaxf(v0[e], 0.f);
                pkb[4 + e] = (__bf16)fmaxf(v1[e], 0.f);
            }
            *(bf16x8*)(trow + ((r0c * 2) ^ swz)) = pkb;
        }
    }
    __syncthreads();

    const float* da_b = da + (size_t)(b * LL) * HH;
    const int rswz = (lo & 7) << 4;

    // --- GEMM1 (C[k][j]) + tanh partials, j in two halves ---
#pragma unroll
    for (int jh = 0; jh < 2; jh++) {
        f32x4 acc[4];
#pragma unroll
        for (int m = 0; m < 4; m++) {
            int j0 = (jh * 4 + m) * 16 + lo;
            acc[m] = *(const f32x4*)(da_b + (size_t)j0 * HH + kq);
        }
#pragma unroll
        for (int ks = 0; ks < 4; ks++) {
            bf16x8 tf[4];
#pragma unroll
            for (int m = 0; m < 4; m++) {
                int row = (jh * 4 + m) * 16 + lo;
                tf[m] = *(const bf16x8*)((const char*)t_lds + row * 256 + ((ks * 64 + g4 * 16) ^ rswz));
            }
#pragma unroll
            for (int m = 0; m < 4; m++) acc[m] = MFMA_B16(Bf[ks], tf[m], acc[m]);
        }
#pragma unroll
        for (int m = 0; m < 4; m++) {
            f32x4 s = acc[m] + ba4;
            float p0 = tanh_fast(s[0]) * wa4[0];
            float p1 = tanh_fast(s[1]) * wa4[1];
            float p2 = tanh_fast(s[2]) * wa4[2];
            float p3 = tanh_fast(s[3]) * wa4[3];
            float p = (p0 + p1) + (p2 + p3);
            p += __shfl_xor(p, 16);
            p += __shfl_xor(p, 32);
            if (g4 == 0) bufA[wv * LL + (jh * 4 + m) * 16 + lo] = p;
        }
    }

    // preload B2 (MmT)
#pragma unroll
    for (int ks = 0; ks < 4; ks++)
        Bf[ks] = *(const bf16x8*)(MmT + (size_t)l * HH * HH + (size_t)(wv * 16 + lo) * HH + ks * 32 + g4 * 8);
    __syncthreads();

    // --- redundant per-wave softmax -> w_lds ---
    {
        const float inv = 0.08838834764831845f;  // 1/sqrt(128)
        float vi = val_s[i];
        float a0 = ba2l, a1 = ba2l;
#pragma unroll
        for (int w = 0; w < 8; w++) {
            a0 += bufA[w * LL + lane];
            a1 += bufA[w * LL + 64 + lane];
        }
        a0 *= inv; a1 *= inv;
        if (!(val_s[lane] > 0.f) || !(vi > 0.f)) a0 = -1e9f;
        if (!(val_s[64 + lane] > 0.f) || !(vi > 0.f)) a1 = -1e9f;
        float m = fmaxf(a0, a1);
#pragma unroll
        for (int d = 1; d < 64; d <<= 1) m = fmaxf(m, __shfl_xor(m, d));
        float e0 = __expf(a0 - m), e1 = __expf(a1 - m);
        float s = e0 + e1;
#pragma unroll
        for (int d = 1; d < 64; d <<= 1) s += __shfl_xor(s, d);
        float rs = 1.f / s;
        w_lds[lane] = e0 * rs;
        w_lds[64 + lane] = e1 * rs;
    }

    // --- GEMM2 (C[k][j]) + weighted relu-msg sum over j (vector fma/max) ---
    f32x4 macv = (f32x4){0.f, 0.f, 0.f, 0.f};
#pragma unroll
    for (int jh = 0; jh < 2; jh++) {
        f32x4 acc[4];
#pragma unroll
        for (int m = 0; m < 4; m++) acc[m] = (f32x4){0.f, 0.f, 0.f, 0.f};
#pragma unroll
        for (int ks = 0; ks < 4; ks++) {
            bf16x8 tf[4];
#pragma unroll
            for (int m = 0; m < 4; m++) {
                int row = (jh * 4 + m) * 16 + lo;
                tf[m] = *(const bf16x8*)((const char*)t_lds + row * 256 + ((ks * 64 + g4 * 16) ^ rswz));
            }
#pragma unroll
            for (int m = 0; m < 4; m++) acc[m] = MFMA_B16(Bf[ks], tf[m], acc[m]);
        }
#pragma unroll
        for (int m = 0; m < 4; m++) {
            float wj = w_lds[(jh * 4 + m) * 16 + lo];
            f32x4 mm = acc[m] + bm4;
#pragma unroll
            for (int rg = 0; rg < 4; rg++) mm[rg] = fmaxf(mm[rg], 0.f);
            macv += mm * wj;
        }
    }
#pragma unroll
    for (int rg = 0; rg < 4; rg++) {
        macv[rg] += __shfl_xor(macv[rg], 1);
        macv[rg] += __shfl_xor(macv[rg], 2);
        macv[rg] += __shfl_xor(macv[rg], 4);
        macv[rg] += __shfl_xor(macv[rg], 8);
    }
    if (lo == 0) *(f32x4*)(v_out + (size_t)bi * HH + kq) = macv;
}

// ---------------- batched post + optional fused pre + fused decoder (last layer) ----------------
__global__ __launch_bounds__(256) void k_post(
    const float* __restrict__ v, const float* __restrict__ oa_in, const float* __restrict__ h,
    const float* __restrict__ mask, const short* __restrict__ WT3,
    const float* __restrict__ bm2, const float* __restrict__ bo1, const float* __restrict__ bo2,
    const float* __restrict__ ln_g, const float* __restrict__ ln_b,
    float* __restrict__ hout, float* __restrict__ hcopy, int l,
    int do_pre, const short* __restrict__ WT4, const float* __restrict__ ca, const float* __restrict__ cm,
    float* __restrict__ base_a, float* __restrict__ da, float* __restrict__ base_m, float* __restrict__ oa_out,
    const float* __restrict__ hist, const float* __restrict__ hg, const float* __restrict__ hb,
    const float* __restrict__ Wh1, const float* __restrict__ bh1,
    const float* __restrict__ Wh2, const float* __restrict__ bh2, float* __restrict__ dec_out) {
    __shared__ __align__(16) short xA[16][136];
    __shared__ __align__(16) short iA[16][136];
    __shared__ float red[2][4][16];
    __shared__ float ln_row[HH];
    __shared__ float dec_x[D_IN + HH];
    const int tid = threadIdx.x, lane = tid & 63, wv = tid >> 6;
    const int lo = lane & 15, g4 = lane >> 4;
    const int r0 = blockIdx.x * 16;

    float oaR[2][4], hR[2][4], vmR[4];
    float bm2R[2], bo1R[2], bo2R[2], gR[2], bR[2];
#pragma unroll
    for (int ct = 0; ct < 2; ct++) {
        int c = wv * 32 + ct * 16 + lo;
        bm2R[ct] = bm2[l * HH + c];
        bo1R[ct] = bo1[l * HH + c];
        bo2R[ct] = bo2[l * HH + c];
        gR[ct] = ln_g[l * HH + c];
        bR[ct] = ln_b[l * HH + c];
    }
#pragma unroll
    for (int rg = 0; rg < 4; rg++) {
        int r = r0 + g4 * 4 + rg;
        vmR[rg] = mask[r];
#pragma unroll
        for (int ct = 0; ct < 2; ct++) {
            int c = wv * 32 + ct * 16 + lo;
            oaR[ct][rg] = oa_in[(size_t)r * HH + c];
            hR[ct][rg] = h[(size_t)r * HH + c];
        }
    }

    int lastRow = -1;
    if (hcopy) {
        float mv = (tid < LL) ? mask[(r0 >> 7) * LL + tid] : 0.f;
#pragma unroll
        for (int d = 1; d < 64; d <<= 1) mv += __shfl_xor(mv, d);
        if (lane == 0) red[0][wv][0] = mv;
    }

    {
        int row = tid >> 4, cc = (tid & 15) * 8;
        const float* vr = v + (size_t)(r0 + row) * HH + cc;
        short8v pk;
#pragma unroll
        for (int e = 0; e < 8; e++) pk[e] = f2bf(vr[e]);
        *(short8v*)&xA[row][cc] = pk;
    }
    __syncthreads();

    if (hcopy) {
        int vc = (int)(red[0][0][0] + red[0][1][0] + red[0][2][0] + red[0][3][0]);
        vc = min(max(vc, 1), LL);
        lastRow = (r0 & ~(LL - 1)) + vc - 1;
    }

    bf16x8 af[4], Bf[2][4];
    f32x4 acc[2];

    // ---- GEMM A: agg = v @ Wm2^T + bm2 -> iA ----
    {
        const short* W = WT3 + (size_t)(l * 3 + 0) * HH * HH;
#pragma unroll
        for (int ks = 0; ks < 4; ks++) af[ks] = *(const bf16x8*)&xA[lo][ks * 32 + g4 * 8];
#pragma unroll
        for (int ct = 0; ct < 2; ct++) {
            int col = wv * 32 + ct * 16 + lo;
#pragma unroll
            for (int ks = 0; ks < 4; ks++)
                Bf[ct][ks] = *(const bf16x8*)(W + (size_t)col * HH + ks * 32 + g4 * 8);
        }
        acc[0] = (f32x4){0.f, 0.f, 0.f, 0.f};
        acc[1] = (f32x4){0.f, 0.f, 0.f, 0.f};
#pragma unroll
        for (int ks = 0; ks < 4; ks++) {
            acc[0] = MFMA_B16(af[ks], Bf[0][ks], acc[0]);
            acc[1] = MFMA_B16(af[ks], Bf[1][ks], acc[1]);
        }
#pragma unroll
        for (int ct = 0; ct < 2; ct++)
#pragma unroll
            for (int rg = 0; rg < 4; rg++)
                iA[g4 * 4 + rg][wv * 32 + ct * 16 + lo] = f2bf(acc[ct][rg] + bm2R[ct]);
    }
    __syncthreads();

    // ---- GEMM B: x1 = relu(agg @ Wo1H^T + oa + bo1) -> xA ----
    {
        const short* W = WT3 + (size_t)(l * 3 + 1) * HH * HH;
#pragma unroll
        for (int ks = 0; ks < 4; ks++) af[ks] = *(const bf16x8*)&iA[lo][ks * 32 + g4 * 8];
#pragma unroll
        for (int ct = 0; ct < 2; ct++) {
            int col = wv * 32 + ct * 16 + lo;
#pragma unroll
            for (int ks = 0; ks < 4; ks++)
                Bf[ct][ks] = *(const bf16x8*)(W + (size_t)col * HH + ks * 32 + g4 * 8);
        }
        acc[0] = (f32x4){0.f, 0.f, 0.f, 0.f};
        acc[1] = (f32x4){0.f, 0.f, 0.f, 0.f};
#pragma unroll
        for (int ks = 0; ks < 4; ks++) {
            acc[0] = MFMA_B16(af[ks], Bf[0][ks], acc[0]);
            acc[1] = MFMA_B16(af[ks], Bf[1][ks], acc[1]);
        }
        __syncthreads();
#pragma unroll
        for (int ct = 0; ct < 2; ct++)
#pragma unroll
            for (int rg = 0; rg < 4; rg++)
                xA[g4 * 4 + rg][wv * 32 + ct * 16 + lo] =
                    f2bf(fmaxf(acc[ct][rg] + oaR[ct][rg] + bo1R[ct], 0.f));
    }
    __syncthreads();

    // ---- GEMM C: y = x1 @ Wo2^T + bo2 + h; LayerNorm ----
    float y[2][4];
    {
        const short* W = WT3 + (size_t)(l * 3 + 2) * HH * HH;
#pragma unroll
        for (int ks = 0; ks < 4; ks++) af[ks] = *(const bf16x8*)&xA[lo][ks * 32 + g4 * 8];
#pragma unroll
        for (int ct = 0; ct < 2; ct++) {
            int col = wv * 32 + ct * 16 + lo;
#pragma unroll
            for (int ks = 0; ks < 4; ks++)
                Bf[ct][ks] = *(const bf16x8*)(W + (size_t)col * HH + ks * 32 + g4 * 8);
        }
        acc[0] = (f32x4){0.f, 0.f, 0.f, 0.f};
        acc[1] = (f32x4){0.f, 0.f, 0.f, 0.f};
#pragma unroll
        for (int ks = 0; ks < 4; ks++) {
            acc[0] = MFMA_B16(af[ks], Bf[0][ks], acc[0]);
            acc[1] = MFMA_B16(af[ks], Bf[1][ks], acc[1]);
        }
#pragma unroll
        for (int ct = 0; ct < 2; ct++)
#pragma unroll
            for (int rg = 0; rg < 4; rg++)
                y[ct][rg] = acc[ct][rg] + bo2R[ct] + hR[ct][rg];
    }
#pragma unroll
    for (int rg = 0; rg < 4; rg++) {
        float s = y[0][rg] + y[1][rg];
        float s2 = y[0][rg] * y[0][rg] + y[1][rg] * y[1][rg];
#pragma unroll
        for (int d = 1; d < 16; d <<= 1) { s += __shfl_xor(s, d); s2 += __shfl_xor(s2, d); }
        if (lo == 0) {
            red[0][wv][g4 * 4 + rg] = s;
            red[1][wv][g4 * 4 + rg] = s2;
        }
    }
    __syncthreads();
#pragma unroll
    for (int rg = 0; rg < 4; rg++) {
        int rl = g4 * 4 + rg;
        float mu = (red[0][0][rl] + red[0][1][rl] + red[0][2][rl] + red[0][3][rl]) * (1.f / HH);
        float ex2 = (red[1][0][rl] + red[1][1][rl] + red[1][2][rl] + red[1][3][rl]) * (1.f / HH);
        float var = ex2 - mu * mu;
        float rs = rsqrtf(var + 1e-5f);
        float vm = vmR[rg] > 0.f ? 1.f : 0.f;
        int r = r0 + rl;
#pragma unroll
        for (int ct = 0; ct < 2; ct++) {
            int c = wv * 32 + ct * 16 + lo;
            float hv = ((y[ct][rg] - mu) * rs * gR[ct] + bR[ct]) * vm;
            hout[(size_t)r * HH + c] = hv;
            if (hcopy) hcopy[(size_t)r * HH + c] = hv;
            if (do_pre) xA[rl][c] = f2bf(hv);
            if (lastRow >= 0 && r == lastRow) ln_row[c] = hv;
        }
    }

    if (do_pre) {
        __syncthreads();
        bf16x8 af2[4];
#pragma unroll
        for (int ks = 0; ks < 4; ks++) af2[ks] = *(const bf16x8*)&xA[lo][ks * 32 + g4 * 8];
        int ln = l + 1;
        const short* Wl = WT4 + (size_t)(ln * 4 + wv) * HH * HH;
        float* dst;
        const float* bias = nullptr;
        if (wv == 0) { dst = base_a; bias = ca + ln * HH; }
        else if (wv == 1) dst = da;
        else if (wv == 2) { dst = base_m; bias = cm + ln * HH; }
        else dst = oa_out;
#pragma unroll
        for (int ct = 0; ct < 8; ct++) {
            int col = ct * 16 + lo;
            bf16x8 Bf2[4];
#pragma unroll
            for (int ks = 0; ks < 4; ks++)
                Bf2[ks] = *(const bf16x8*)(Wl + (size_t)col * HH + ks * 32 + g4 * 8);
            f32x4 a2 = (f32x4){0.f, 0.f, 0.f, 0.f};
#pragma unroll
            for (int ks = 0; ks < 4; ks++) a2 = MFMA_B16(af2[ks], Bf2[ks], a2);
            float bv = bias ? bias[col] : 0.f;
#pragma unroll
            for (int rg = 0; rg < 4; rg++)
                dst[(size_t)(r0 + g4 * 4 + rg) * HH + col] = a2[rg] + bv;
        }
    }

    // ---- fused decoder: only the block owning lastRow ----
    if (hcopy && lastRow >= r0 && lastRow < r0 + 16) {
        const int N = D_IN + HH;  // 136
        __syncthreads();
        if (tid < D_IN) dec_x[tid] = hist[(size_t)lastRow * D_IN + tid];
        if (tid < HH) dec_x[D_IN + tid] = ln_row[tid];
        __syncthreads();
        float px = (tid < N) ? dec_x[tid] : 0.f;
        float px2 = px * px;
#pragma unroll
        for (int d = 1; d < 64; d <<= 1) { px += __shfl_xor(px, d); px2 += __shfl_xor(px2, d); }
        if (lane == 0) { red[0][wv][0] = px; red[1][wv][0] = px2; }
        __syncthreads();
        float mu = (red[0][0][0] + red[0][1][0] + red[0][2][0] + red[0][3][0]) / (float)N;
        float ex2 = (red[1][0][0] + red[1][1][0] + red[1][2][0] + red[1][3][0]) / (float)N;
        float var = ex2 - mu * mu;
        float rs = rsqrtf(var + 1e-5f);
        if (tid < N) dec_x[tid] = (dec_x[tid] - mu) * rs * hg[tid] + hb[tid];
        __syncthreads();
        if (tid < HH) {
            float a = bh1[tid];
            for (int f = 0; f < N; f++) a += dec_x[f] * Wh1[(size_t)f * HH + tid];
            ln_row[tid] = fmaxf(a, 0.f);
        }
        __syncthreads();
        if (tid < FUT * MDIM) {
            float o = bh2[tid];
            for (int k = 0; k < HH; k++) o += ln_row[k] * Wh2[(size_t)k * FUT * MDIM + tid];
            if (isnan(o)) o = 0.f;
            else if (isinf(o)) o = (o > 0.f) ? 1e4f : -1e4f;
            dec_out[(r0 >> 7) * FUT * MDIM + tid] = o;
        }
    }
}

extern "C" void kernel_launch(void* const* d_in, const int* in_sizes, int n_in,
                              void* d_out, int out_size, void* d_ws, size_t ws_size,
                              hipStream_t stream) {
    const float* hist = (const float*)d_in[0];
    const float* mask = (const float*)d_in[1];
    const float* Wp  = (const float*)d_in[2];
    const float* bp  = (const float*)d_in[3];
    const float* We1 = (const float*)d_in[4];
    const float* be1 = (const float*)d_in[5];
    const float* We2 = (const float*)d_in[6];
    const float* be2 = (const float*)d_in[7];
    const float* Wa1 = (const float*)d_in[8];
    const float* ba1 = (const float*)d_in[9];
    const float* wa2 = (const float*)d_in[10];
    const float* ba2 = (const float*)d_in[11];
    const float* Wm1 = (const float*)d_in[12];
    const float* bm1 = (const float*)d_in[13];
    const float* Wm2 = (const float*)d_in[14];
    const float* bm2 = (const float*)d_in[15];
    const float* Wo1 = (const float*)d_in[16];
    const float* bo1 = (const float*)d_in[17];
    const float* Wo2 = (const float*)d_in[18];
    const float* bo2 = (const float*)d_in[19];
    const float* ln_g = (const float*)d_in[20];
    const float* ln_b = (const float*)d_in[21];
    const float* hg  = (const float*)d_in[22];
    const float* hb  = (const float*)d_in[23];
    const float* Wh1 = (const float*)d_in[24];
    const float* bh1 = (const float*)d_in[25];
    const float* Wh2 = (const float*)d_in[26];
    const float* bh2 = (const float*)d_in[27];
    float* out = (float*)d_out;

    float* ws = (float*)d_ws;
    float* ts_w   = ws; ws += BB * LL;
    float* h_w    = ws; ws += BB * LL * HH;
    float* da_w   = ws; ws += BB * LL * HH;
    float* ba_w   = ws; ws += BB * LL * HH;   // base_a
    float* bm_w   = ws; ws += BB * LL * HH;   // base_m
    float* oa_w   = ws; ws += BB * LL * HH;
    float* v_w    = ws; ws += BB * LL * HH;
    float* ca_w   = ws; ws += NLAYER * HH;
    float* cm_w   = ws; ws += NLAYER * HH;
    short* AmT_w  = (short*)ws; ws += NLAYER * HH * HH / 2;
    short* MmT_w  = (short*)ws; ws += NLAYER * HH * HH / 2;
    short* WT4_w  = (short*)ws; ws += NLAYER * 4 * HH * HH / 2;
    short* WT3_w  = (short*)ws; ws += NLAYER * 3 * HH * HH / 2;

    const int NPREP = BB + NLAYER * (HH + 1) + NLAYER * 7;
    k_prep<<<NPREP, 256, 0, stream>>>(hist, mask, Wp, bp, We2, be2, Wa1, ba1, Wm1, bm1,
                                      Wo1, Wm2, Wo2, ts_w, h_w, AmT_w, MmT_w, ca_w, cm_w, WT4_w, WT3_w);
    k_pre<<<BB * LL / 16 * 2, 256, 0, stream>>>(h_w, WT4_w, ca_w, cm_w, ba_w, da_w, bm_w, oa_w, 0);
    for (int l = 0; l < NLAYER; l++) {
        k_attn<<<BB * LL, 512, 0, stream>>>(hist, mask, ts_w, ba_w, bm_w, da_w, AmT_w, MmT_w,
                                            wa2, ba2, We1, be1, v_w, l);
        int do_pre = (l < NLAYER - 1) ? 1 : 0;
        float* hcopy = (l == NLAYER - 1) ? (out + BB * FUT * MDIM) : nullptr;
        k_post<<<BB * LL / 16, 256, 0, stream>>>(v_w, oa_w, h_w, mask, WT3_w, bm2, bo1, bo2,
                                                 ln_g, ln_b, h_w, hcopy, l,
                                                 do_pre, WT4_w, ca_w, cm_w, ba_w, da_w, bm_w, oa_w,
                                                 hist, hg, hb, Wh1, bh1, Wh2, bh2, out);
    }
}

// Round 11
// 255.962 us; speedup vs baseline: 1.0101x; 1.0101x over previous
//
#include <hip/hip_runtime.h>
#include <math.h>

#define BB 16
#define LL 128
#define D_IN 8
#define HH 128
#define NLAYER 2
#define FUT 12
#define MDIM 2

typedef __attribute__((ext_vector_type(8))) __bf16 bf16x8;
typedef __attribute__((ext_vector_type(8))) short short8v;
typedef __attribute__((ext_vector_type(4))) short short4v;
typedef __attribute__((ext_vector_type(4))) float f32x4;

#define MFMA_B16(A, B, C) __builtin_amdgcn_mfma_f32_16x16x32_bf16(A, B, C, 0, 0, 0)

static __device__ __forceinline__ short f2bf(float f) {
    union { float f; unsigned u; } v; v.f = f;
    unsigned r = v.u + 0x7FFFu + ((v.u >> 16) & 1u);
    return (short)(r >> 16);
}

static __device__ __forceinline__ float tanh_fast(float x) {
    float e = __expf(2.f * x);
    return 1.f - 2.f / (e + 1.f);
}

// ---------------- merged prep: ts+h0 (LDS-staged) | compose (split-K) | weight transpose ----------------
__global__ __launch_bounds__(256) void k_prep(const float* __restrict__ hist, const float* __restrict__ mask,
                                              const float* __restrict__ Wp, const float* __restrict__ bp,
                                              const float* __restrict__ We2, const float* __restrict__ be2,
                                              const float* __restrict__ Wa1, const float* __restrict__ ba1,
                                              const float* __restrict__ Wm1, const float* __restrict__ bm1,
                                              const float* __restrict__ Wo1, const float* __restrict__ Wm2,
                                              const float* __restrict__ Wo2,
                                              float* __restrict__ ts, float* __restrict__ h,
                                              short* __restrict__ AmT, short* __restrict__ MmT,
                                              float* __restrict__ ca, float* __restrict__ cm,
                                              short* __restrict__ WT4, short* __restrict__ WT3) {
    __shared__ float row[HH];
    __shared__ float pa[256], pm[256];
    __shared__ float hrow[LL * D_IN];
    const int bid = blockIdx.x, tid = threadIdx.x;
    const int NC = NLAYER * (HH + 1);
    if (bid < BB) {
        int b = bid;
        // stage hist rows + mask for this batch into LDS
#pragma unroll
        for (int e = 0; e < 4; e++) hrow[e * 256 + tid] = hist[(size_t)b * LL * D_IN + e * 256 + tid];
        if (tid < LL) pa[tid] = mask[b * LL + tid];
        __syncthreads();
        if (tid < LL) row[tid] = fmaxf(hrow[tid * D_IN + 5], 0.f);
        __syncthreads();
        for (int d = 1; d < LL; d <<= 1) {
            float add = (tid < LL && tid >= d) ? row[tid - d] : 0.f;
            __syncthreads();
            if (tid < LL) row[tid] += add;
            __syncthreads();
        }
        if (tid < LL) ts[b * LL + tid] = row[tid];
        int k = tid & (HH - 1);
        float wp_r[D_IN];
#pragma unroll
        for (int f = 0; f < D_IN; f++) wp_r[f] = Wp[f * HH + k];
        float bpk = bp[k];
        int jbase = tid >> 7;
        for (int e = 0; e < 64; e++) {
            int j = e * 2 + jbase;
            const float* hr = &hrow[j * D_IN];
            float acc = bpk;
#pragma unroll
            for (int f = 0; f < D_IN; f++) acc += hr[f] * wp_r[f];
            h[(size_t)(b * LL + j) * HH + k] = acc * (pa[j] > 0.f ? 1.f : 0.f);
        }
    } else if (bid < BB + NC) {
        int cb = bid - BB;
        int l = cb / (HH + 1);
        int p = cb % (HH + 1);
        const float* WaE = Wa1 + (size_t)(l * 3 * HH + 2 * HH) * HH;
        const float* WmE = Wm1 + (size_t)(l * 2 * HH + HH) * HH;
        int q = tid & 127, kh = tid >> 7;
        if (tid < HH) row[tid] = (p < HH) ? We2[(size_t)(l * HH + p) * HH + tid] : be2[l * HH + tid];
        __syncthreads();
        float a = 0.f, m = 0.f;
        int kbase = kh * 64;
#pragma unroll 4
        for (int k = 0; k < 64; k++) {
            float w = row[kbase + k];
            a += w * WaE[(size_t)(kbase + k) * HH + q];
            m += w * WmE[(size_t)(kbase + k) * HH + q];
        }
        pa[tid] = a;
        pm[tid] = m;
        __syncthreads();
        if (tid < HH) {
            a = pa[tid] + pa[128 + tid];
            m = pm[tid] + pm[128 + tid];
            if (p < HH) {
                AmT[(size_t)l * HH * HH + tid * HH + p] = f2bf(a);
                MmT[(size_t)l * HH * HH + tid * HH + p] = f2bf(m);
            } else {
                ca[l * HH + tid] = a + ba1[l * HH + tid];
                cm[l * HH + tid] = m + bm1[l * HH + tid];
            }
        }
    } else {
        int m7 = bid - BB - NC;
        int l = m7 / 7, m = m7 % 7;
        const float* src;
        switch (m) {
            case 0: src = Wa1 + (size_t)(l * 3 * HH) * HH; break;
            case 1: src = Wa1 + (size_t)(l * 3 * HH + HH) * HH; break;
            case 2: src = Wm1 + (size_t)(l * 2 * HH) * HH; break;
            case 3: src = Wo1 + (size_t)(l * 2 * HH) * HH; break;
            case 4: src = Wm2 + (size_t)l * HH * HH; break;
            case 5: src = Wo1 + (size_t)(l * 2 * HH + HH) * HH; break;
            default: src = Wo2 + (size_t)l * HH * HH; break;
        }
        short* dst = (m < 4) ? (WT4 + (size_t)(l * 4 + m) * HH * HH)
                             : (WT3 + (size_t)(l * 3 + (m - 4)) * HH * HH);
#pragma unroll 4
        for (int e = 0; e < 64; e++) {
            int idx = e * 256 + tid;
            int kk = idx >> 7;
            int c = idx & 127;
            dst[c * HH + kk] = f2bf(src[(size_t)kk * HH + c]);
        }
    }
}

// ---------------- batched pre-projections, 128 blocks x 512 threads ----------------
__global__ __launch_bounds__(512) void k_pre(const float* __restrict__ h, const short* __restrict__ WT4,
                                             const float* __restrict__ ca, const float* __restrict__ cm,
                                             float* __restrict__ base_a, float* __restrict__ da,
                                             float* __restrict__ base_m, float* __restrict__ oa, int l) {
    __shared__ __align__(16) short hA[16][136];
    const int tid = threadIdx.x, lane = tid & 63, wv = tid >> 6;
    const int lo = lane & 15, g4 = lane >> 4;
    const int r0 = blockIdx.x * 16;
    const int mat = wv >> 1, colh = wv & 1;

    // prefetch ALL weight fragments for this wave (issue before LDS stage completes)
    const short* Wl = WT4 + (size_t)(l * 4 + mat) * HH * HH;
    bf16x8 Bf[4][4];
#pragma unroll
    for (int t = 0; t < 4; t++) {
        int col = (colh * 4 + t) * 16 + lo;
#pragma unroll
        for (int ks = 0; ks < 4; ks++)
            Bf[t][ks] = *(const bf16x8*)(Wl + (size_t)col * HH + ks * 32 + g4 * 8);
    }

    {
        int row = tid >> 5, cc = (tid & 31) * 4;
        const float* hr = h + (size_t)(r0 + row) * HH + cc;
        short4v pk;
#pragma unroll
        for (int e = 0; e < 4; e++) pk[e] = f2bf(hr[e]);
        *(short4v*)&hA[row][cc] = pk;
    }
    __syncthreads();
    bf16x8 af[4];
#pragma unroll
    for (int ks = 0; ks < 4; ks++)
        af[ks] = *(const bf16x8*)&hA[lo][ks * 32 + g4 * 8];
    float* dst;
    const float* bias = nullptr;
    if (mat == 0) { dst = base_a; bias = ca + l * HH; }
    else if (mat == 1) dst = da;
    else if (mat == 2) { dst = base_m; bias = cm + l * HH; }
    else dst = oa;
#pragma unroll
    for (int t = 0; t < 4; t++) {
        int col = (colh * 4 + t) * 16 + lo;
        f32x4 acc = (f32x4){0.f, 0.f, 0.f, 0.f};
#pragma unroll
        for (int ks = 0; ks < 4; ks++) acc = MFMA_B16(af[ks], Bf[t][ks], acc);
        float bv = bias ? bias[col] : 0.f;
#pragma unroll
        for (int rg = 0; rg < 4; rg++)
            dst[(size_t)(r0 + g4 * 4 + rg) * HH + col] = acc[rg] + bv;
    }
}

// ---------------- attention core: 512 threads, C[k][j], packed-fp32 t-compute ----------------
__global__ __launch_bounds__(512) void k_attn(
    const float* __restrict__ hist, const float* __restrict__ mask, const float* __restrict__ ts,
    const float* __restrict__ base_a_g, const float* __restrict__ base_m_g, const float* __restrict__ da,
    const short* __restrict__ AmT, const short* __restrict__ MmT,
    const float* __restrict__ wa2, const float* __restrict__ ba2,
    const float* __restrict__ We1, const float* __restrict__ be1,
    float* __restrict__ v_out, int l) {
    __shared__ __align__(16) short t_lds[LL][LL];    // 32768 B, XOR-swizzled
    __shared__ __align__(16) float bufA[1024];
    __shared__ float w_lds[LL];
    __shared__ float val_s[LL];

    const int tid = threadIdx.x;
    const int lane = tid & 63;
    const int wv = tid >> 6;
    const int lo = lane & 15, g4 = lane >> 4;
    const int kq = wv * 16 + g4 * 4;
    const int bi = blockIdx.x, b = bi >> 7, i = bi & (LL - 1);

    const f32x4 ba4 = *(const f32x4*)(base_a_g + (size_t)bi * HH + kq);
    const f32x4 bm4 = *(const f32x4*)(base_m_g + (size_t)bi * HH + kq);
    const f32x4 wa4 = *(const f32x4*)(wa2 + l * HH + kq);
    const float ba2l = ba2[l];

    bf16x8 Bf[4];
#pragma unroll
    for (int ks = 0; ks < 4; ks++)
        Bf[ks] = *(const bf16x8*)(AmT + (size_t)l * HH * HH + (size_t)(wv * 16 + lo) * HH + ks * 32 + g4 * 8);

    {
        const float* We1l = We1 + l * 4 * HH;
        const float* be1l = be1 + l * HH;
        if (tid < 256) bufA[tid] = We1l[tid];
        else if (tid < 384) bufA[tid] = be1l[tid - 256];
        else bufA[tid] = be1l[tid - 384] + We1l[256 + (tid - 384)];
        if (tid < 128) {
            bufA[512 + tid] = We1l[384 + tid];
            val_s[tid] = mask[b * LL + tid];
        }
    }
    __syncthreads();

    {
        int jj = tid & (LL - 1);
        int q4 = tid >> 7;
        const float* hri = hist + (size_t)(b * LL + i) * D_IN;
        const float* hrj = hist + (size_t)(b * LL + jj) * D_IN;
        float dlat = hri[0] - hrj[0], dlon = hri[1] - hrj[1];
        float ea = sqrtf(dlat * dlat + dlon * dlon + 1e-8f);
        float eb = fabsf(ts[b * LL + i] - ts[b * LL + jj]) * (1.f / 300.f);
        const float* basep = bufA + ((hri[6] == hrj[6]) ? 384 : 256);
        char* trow = (char*)t_lds + jj * 256;
        int swz = (jj & 7) << 4;
        bool diag = (jj == i);
#pragma unroll
        for (int pass = 0; pass < 4; pass++) {
            int r0c = (q4 + pass * 4) * 8;
            f32x4 v0, v1;
            {
                f32x4 wa0 = *(const f32x4*)&bufA[r0c];
                f32x4 wb0 = *(const f32x4*)&bufA[128 + r0c];
                f32x4 bs0 = *(const f32x4*)&basep[r0c];
                v0 = wa0 * ea + wb0 * eb + bs0;
                f32x4 wa1 = *(const f32x4*)&bufA[r0c + 4];
                f32x4 wb1 = *(const f32x4*)&bufA[128 + r0c + 4];
                f32x4 bs1 = *(const f32x4*)&basep[r0c + 4];
                v1 = wa1 * ea + wb1 * eb + bs1;
            }
            if (diag) {
                v0 += *(const f32x4*)&bufA[512 + r0c];
                v1 += *(const f32x4*)&bufA[512 + r0c + 4];
            }
            bf16x8 pkb;
#pragma unroll
            for (int e = 0; e < 4; e++) {
                pkb[e] = (__bf16)fmaxf(v0[e], 0.f);
                pkb[4 + e] = (__bf16)fmaxf(v1[e], 0.f);
            }
            *(bf16x8*)(trow + ((r0c * 2) ^ swz)) = pkb;
        }
    }
    __syncthreads();

    const float* da_b = da + (size_t)(b * LL) * HH;
    const int rswz = (lo & 7) << 4;

#pragma unroll
    for (int jh = 0; jh < 2; jh++) {
        f32x4 acc[4];
#pragma unroll
        for (int m = 0; m < 4; m++) {
            int j0 = (jh * 4 + m) * 16 + lo;
            acc[m] = *(const f32x4*)(da_b + (size_t)j0 * HH + kq);
        }
#pragma unroll
        for (int ks = 0; ks < 4; ks++) {
            bf16x8 tf[4];
#pragma unroll
            for (int m = 0; m < 4; m++) {
                int row = (jh * 4 + m) * 16 + lo;
                tf[m] = *(const bf16x8*)((const char*)t_lds + row * 256 + ((ks * 64 + g4 * 16) ^ rswz));
            }
#pragma unroll
            for (int m = 0; m < 4; m++) acc[m] = MFMA_B16(Bf[ks], tf[m], acc[m]);
        }
#pragma unroll
        for (int m = 0; m < 4; m++) {
            f32x4 s = acc[m] + ba4;
            float p0 = tanh_fast(s[0]) * wa4[0];
            float p1 = tanh_fast(s[1]) * wa4[1];
            float p2 = tanh_fast(s[2]) * wa4[2];
            float p3 = tanh_fast(s[3]) * wa4[3];
            float p = (p0 + p1) + (p2 + p3);
            p += __shfl_xor(p, 16);
            p += __shfl_xor(p, 32);
            if (g4 == 0) bufA[wv * LL + (jh * 4 + m) * 16 + lo] = p;
        }
    }

#pragma unroll
    for (int ks = 0; ks < 4; ks++)
        Bf[ks] = *(const bf16x8*)(MmT + (size_t)l * HH * HH + (size_t)(wv * 16 + lo) * HH + ks * 32 + g4 * 8);
    __syncthreads();

    {
        const float inv = 0.08838834764831845f;
        float vi = val_s[i];
        float a0 = ba2l, a1 = ba2l;
#pragma unroll
        for (int w = 0; w < 8; w++) {
            a0 += bufA[w * LL + lane];
            a1 += bufA[w * LL + 64 + lane];
        }
        a0 *= inv; a1 *= inv;
        if (!(val_s[lane] > 0.f) || !(vi > 0.f)) a0 = -1e9f;
        if (!(val_s[64 + lane] > 0.f) || !(vi > 0.f)) a1 = -1e9f;
        float m = fmaxf(a0, a1);
#pragma unroll
        for (int d = 1; d < 64; d <<= 1) m = fmaxf(m, __shfl_xor(m, d));
        float e0 = __expf(a0 - m), e1 = __expf(a1 - m);
        float s = e0 + e1;
#pragma unroll
        for (int d = 1; d < 64; d <<= 1) s += __shfl_xor(s, d);
        float rs = 1.f / s;
        w_lds[lane] = e0 * rs;
        w_lds[64 + lane] = e1 * rs;
    }

    f32x4 macv = (f32x4){0.f, 0.f, 0.f, 0.f};
#pragma unroll
    for (int jh = 0; jh < 2; jh++) {
        f32x4 acc[4];
#pragma unroll
        for (int m = 0; m < 4; m++) acc[m] = (f32x4){0.f, 0.f, 0.f, 0.f};
#pragma unroll
        for (int ks = 0; ks < 4; ks++) {
            bf16x8 tf[4];
#pragma unroll
            for (int m = 0; m < 4; m++) {
                int row = (jh * 4 + m) * 16 + lo;
                tf[m] = *(const bf16x8*)((const char*)t_lds + row * 256 + ((ks * 64 + g4 * 16) ^ rswz));
            }
#pragma unroll
            for (int m = 0; m < 4; m++) acc[m] = MFMA_B16(Bf[ks], tf[m], acc[m]);
        }
#pragma unroll
        for (int m = 0; m < 4; m++) {
            float wj = w_lds[(jh * 4 + m) * 16 + lo];
            f32x4 mm = acc[m] + bm4;
#pragma unroll
            for (int rg = 0; rg < 4; rg++) mm[rg] = fmaxf(mm[rg], 0.f);
            macv += mm * wj;
        }
    }
#pragma unroll
    for (int rg = 0; rg < 4; rg++) {
        macv[rg] += __shfl_xor(macv[rg], 1);
        macv[rg] += __shfl_xor(macv[rg], 2);
        macv[rg] += __shfl_xor(macv[rg], 4);
        macv[rg] += __shfl_xor(macv[rg], 8);
    }
    if (lo == 0) *(f32x4*)(v_out + (size_t)bi * HH + kq) = macv;
}

// ---------------- batched post, 128 blocks x 512 threads: wave owns 16 cols ----------------
__global__ __launch_bounds__(512) void k_post(
    const float* __restrict__ v, const float* __restrict__ oa_in, const float* __restrict__ h,
    const float* __restrict__ mask, const short* __restrict__ WT3,
    const float* __restrict__ bm2, const float* __restrict__ bo1, const float* __restrict__ bo2,
    const float* __restrict__ ln_g, const float* __restrict__ ln_b,
    float* __restrict__ hout, float* __restrict__ hcopy, int l,
    int do_pre, const short* __restrict__ WT4, const float* __restrict__ ca, const float* __restrict__ cm,
    float* __restrict__ base_a, float* __restrict__ da, float* __restrict__ base_m, float* __restrict__ oa_out,
    const float* __restrict__ hist, const float* __restrict__ hg, const float* __restrict__ hb,
    const float* __restrict__ Wh1, const float* __restrict__ bh1,
    const float* __restrict__ Wh2, const float* __restrict__ bh2, float* __restrict__ dec_out) {
    __shared__ __align__(16) short xA[16][136];
    __shared__ __align__(16) short iA[16][136];
    __shared__ float red[2][8][16];
    __shared__ float ln_row[HH];
    __shared__ float dec_x[D_IN + HH];
    const int tid = threadIdx.x, lane = tid & 63, wv = tid >> 6;
    const int lo = lane & 15, g4 = lane >> 4;
    const int r0 = blockIdx.x * 16;
    const int c = wv * 16 + lo;      // this thread's column

    // prefetch ALL GEMM weight fragments (A, B, C) — one L2 latency, hidden under staging
    bf16x8 BfA[4], BfB[4], BfC[4];
    {
        const short* WA = WT3 + (size_t)(l * 3 + 0) * HH * HH;
        const short* WB = WT3 + (size_t)(l * 3 + 1) * HH * HH;
        const short* WC = WT3 + (size_t)(l * 3 + 2) * HH * HH;
#pragma unroll
        for (int ks = 0; ks < 4; ks++) {
            BfA[ks] = *(const bf16x8*)(WA + (size_t)c * HH + ks * 32 + g4 * 8);
            BfB[ks] = *(const bf16x8*)(WB + (size_t)c * HH + ks * 32 + g4 * 8);
            BfC[ks] = *(const bf16x8*)(WC + (size_t)c * HH + ks * 32 + g4 * 8);
        }
    }

    // epilogue operands
    float oaR[4], hR[4], vmR[4];
    const float bm2R = bm2[l * HH + c], bo1R = bo1[l * HH + c], bo2R = bo2[l * HH + c];
    const float gR = ln_g[l * HH + c], bR = ln_b[l * HH + c];
#pragma unroll
    for (int rg = 0; rg < 4; rg++) {
        int r = r0 + g4 * 4 + rg;
        vmR[rg] = mask[r];
        oaR[rg] = oa_in[(size_t)r * HH + c];
        hR[rg] = h[(size_t)r * HH + c];
    }

    int lastRow = -1;
    if (hcopy) {
        float mv = (tid < LL) ? mask[(r0 >> 7) * LL + tid] : 0.f;
#pragma unroll
        for (int d = 1; d < 64; d <<= 1) mv += __shfl_xor(mv, d);
        if (lane == 0) red[0][wv][0] = mv;
    }

    // stage v -> xA bf16
    {
        int row = tid >> 5, cc = (tid & 31) * 4;
        const float* vr = v + (size_t)(r0 + row) * HH + cc;
        short4v pk;
#pragma unroll
        for (int e = 0; e < 4; e++) pk[e] = f2bf(vr[e]);
        *(short4v*)&xA[row][cc] = pk;
    }
    __syncthreads();

    if (hcopy) {
        float vcs = 0.f;
#pragma unroll
        for (int w = 0; w < 8; w++) vcs += red[0][w][0];
        int vc = (int)vcs;
        vc = min(max(vc, 1), LL);
        lastRow = (r0 & ~(LL - 1)) + vc - 1;
    }

    bf16x8 af[4];
    f32x4 acc;

    // ---- GEMM A: agg = v @ Wm2^T + bm2 -> iA ----
#pragma unroll
    for (int ks = 0; ks < 4; ks++) af[ks] = *(const bf16x8*)&xA[lo][ks * 32 + g4 * 8];
    acc = (f32x4){0.f, 0.f, 0.f, 0.f};
#pragma unroll
    for (int ks = 0; ks < 4; ks++) acc = MFMA_B16(af[ks], BfA[ks], acc);
#pragma unroll
    for (int rg = 0; rg < 4; rg++) iA[g4 * 4 + rg][c] = f2bf(acc[rg] + bm2R);
    __syncthreads();

    // ---- GEMM B: x1 = relu(agg @ Wo1H^T + oa + bo1) -> xA ----
#pragma unroll
    for (int ks = 0; ks < 4; ks++) af[ks] = *(const bf16x8*)&iA[lo][ks * 32 + g4 * 8];
    acc = (f32x4){0.f, 0.f, 0.f, 0.f};
#pragma unroll
    for (int ks = 0; ks < 4; ks++) acc = MFMA_B16(af[ks], BfB[ks], acc);
#pragma unroll
    for (int rg = 0; rg < 4; rg++)
        xA[g4 * 4 + rg][c] = f2bf(fmaxf(acc[rg] + oaR[rg] + bo1R, 0.f));
    __syncthreads();

    // ---- GEMM C: y = x1 @ Wo2^T + bo2 + h; LayerNorm ----
    float y[4];
#pragma unroll
    for (int ks = 0; ks < 4; ks++) af[ks] = *(const bf16x8*)&xA[lo][ks * 32 + g4 * 8];
    acc = (f32x4){0.f, 0.f, 0.f, 0.f};
#pragma unroll
    for (int ks = 0; ks < 4; ks++) acc = MFMA_B16(af[ks], BfC[ks], acc);
#pragma unroll
    for (int rg = 0; rg < 4; rg++) y[rg] = acc[rg] + bo2R + hR[rg];

#pragma unroll
    for (int rg = 0; rg < 4; rg++) {
        float s = y[rg];
        float s2 = y[rg] * y[rg];
#pragma unroll
        for (int d = 1; d < 16; d <<= 1) { s += __shfl_xor(s, d); s2 += __shfl_xor(s2, d); }
        if (lo == 0) {
            red[0][wv][g4 * 4 + rg] = s;
            red[1][wv][g4 * 4 + rg] = s2;
        }
    }
    __syncthreads();
#pragma unroll
    for (int rg = 0; rg < 4; rg++) {
        int rl = g4 * 4 + rg;
        float mu = 0.f, ex2 = 0.f;
#pragma unroll
        for (int w = 0; w < 8; w++) { mu += red[0][w][rl]; ex2 += red[1][w][rl]; }
        mu *= (1.f / HH);
        ex2 *= (1.f / HH);
        float var = ex2 - mu * mu;
        float rs = rsqrtf(var + 1e-5f);
        float vm = vmR[rg] > 0.f ? 1.f : 0.f;
        int r = r0 + rl;
        float hv = ((y[rg] - mu) * rs * gR + bR) * vm;
        hout[(size_t)r * HH + c] = hv;
        if (hcopy) hcopy[(size_t)r * HH + c] = hv;
        if (do_pre) xA[rl][c] = f2bf(hv);
        if (lastRow >= 0 && r == lastRow) ln_row[c] = hv;
    }

    if (do_pre) {
        int ln = l + 1;
        int mat = wv >> 1, colh = wv & 1;
        const short* Wl = WT4 + (size_t)(ln * 4 + mat) * HH * HH;
        bf16x8 Bf2[4][4];
#pragma unroll
        for (int t = 0; t < 4; t++) {
            int col2 = (colh * 4 + t) * 16 + lo;
#pragma unroll
            for (int ks = 0; ks < 4; ks++)
                Bf2[t][ks] = *(const bf16x8*)(Wl + (size_t)col2 * HH + ks * 32 + g4 * 8);
        }
        __syncthreads();
        bf16x8 af2[4];
#pragma unroll
        for (int ks = 0; ks < 4; ks++) af2[ks] = *(const bf16x8*)&xA[lo][ks * 32 + g4 * 8];
        float* dst;
        const float* bias = nullptr;
        if (mat == 0) { dst = base_a; bias = ca + ln * HH; }
        else if (mat == 1) dst = da;
        else if (mat == 2) { dst = base_m; bias = cm + ln * HH; }
        else dst = oa_out;
#pragma unroll
        for (int t = 0; t < 4; t++) {
            int col2 = (colh * 4 + t) * 16 + lo;
            f32x4 a2 = (f32x4){0.f, 0.f, 0.f, 0.f};
#pragma unroll
            for (int ks = 0; ks < 4; ks++) a2 = MFMA_B16(af2[ks], Bf2[t][ks], a2);
            float bv = bias ? bias[col2] : 0.f;
#pragma unroll
            for (int rg = 0; rg < 4; rg++)
                dst[(size_t)(r0 + g4 * 4 + rg) * HH + col2] = a2[rg] + bv;
        }
    }

    // ---- fused decoder: only the block owning lastRow ----
    if (hcopy && lastRow >= r0 && lastRow < r0 + 16) {
        const int N = D_IN + HH;  // 136
        __syncthreads();
        if (tid < D_IN) dec_x[tid] = hist[(size_t)lastRow * D_IN + tid];
        if (tid < HH) dec_x[D_IN + tid] = ln_row[tid];
        __syncthreads();
        float px = (tid < N) ? dec_x[tid] : 0.f;
        float px2 = px * px;
#pragma unroll
        for (int d = 1; d < 64; d <<= 1) { px += __shfl_xor(px, d); px2 += __shfl_xor(px2, d); }
        if (lane == 0) { red[0][wv][0] = px; red[1][wv][0] = px2; }
        __syncthreads();
        float mu = 0.f, ex2 = 0.f;
#pragma unroll
        for (int w = 0; w < 8; w++) { mu += red[0][w][0]; ex2 += red[1][w][0]; }
        mu /= (float)N;
        ex2 /= (float)N;
        float var = ex2 - mu * mu;
        float rs = rsqrtf(var + 1e-5f);
        if (tid < N) dec_x[tid] = (dec_x[tid] - mu) * rs * hg[tid] + hb[tid];
        __syncthreads();
        if (tid < HH) {
            float a = bh1[tid];
            for (int f = 0; f < N; f++) a += dec_x[f] * Wh1[(size_t)f * HH + tid];
            ln_row[tid] = fmaxf(a, 0.f);
        }
        __syncthreads();
        if (tid < FUT * MDIM) {
            float o = bh2[tid];
            for (int k = 0; k < HH; k++) o += ln_row[k] * Wh2[(size_t)k * FUT * MDIM + tid];
            if (isnan(o)) o = 0.f;
            else if (isinf(o)) o = (o > 0.f) ? 1e4f : -1e4f;
            dec_out[(r0 >> 7) * FUT * MDIM + tid] = o;
        }
    }
}

extern "C" void kernel_launch(void* const* d_in, const int* in_sizes, int n_in,
                              void* d_out, int out_size, void* d_ws, size_t ws_size,
                              hipStream_t stream) {
    const float* hist = (const float*)d_in[0];
    const float* mask = (const float*)d_in[1];
    const float* Wp  = (const float*)d_in[2];
    const float* bp  = (const float*)d_in[3];
    const float* We1 = (const float*)d_in[4];
    const float* be1 = (const float*)d_in[5];
    const float* We2 = (const float*)d_in[6];
    const float* be2 = (const float*)d_in[7];
    const float* Wa1 = (const float*)d_in[8];
    const float* ba1 = (const float*)d_in[9];
    const float* wa2 = (const float*)d_in[10];
    const float* ba2 = (const float*)d_in[11];
    const float* Wm1 = (const float*)d_in[12];
    const float* bm1 = (const float*)d_in[13];
    const float* Wm2 = (const float*)d_in[14];
    const float* bm2 = (const float*)d_in[15];
    const float* Wo1 = (const float*)d_in[16];
    const float* bo1 = (const float*)d_in[17];
    const float* Wo2 = (const float*)d_in[18];
    const float* bo2 = (const float*)d_in[19];
    const float* ln_g = (const float*)d_in[20];
    const float* ln_b = (const float*)d_in[21];
    const float* hg  = (const float*)d_in[22];
    const float* hb  = (const float*)d_in[23];
    const float* Wh1 = (const float*)d_in[24];
    const float* bh1 = (const float*)d_in[25];
    const float* Wh2 = (const float*)d_in[26];
    const float* bh2 = (const float*)d_in[27];
    float* out = (float*)d_out;

    float* ws = (float*)d_ws;
    float* ts_w   = ws; ws += BB * LL;
    float* h_w    = ws; ws += BB * LL * HH;
    float* da_w   = ws; ws += BB * LL * HH;
    float* ba_w   = ws; ws += BB * LL * HH;   // base_a
    float* bm_w   = ws; ws += BB * LL * HH;   // base_m
    float* oa_w   = ws; ws += BB * LL * HH;
    float* v_w    = ws; ws += BB * LL * HH;
    float* ca_w   = ws; ws += NLAYER * HH;
    float* cm_w   = ws; ws += NLAYER * HH;
    short* AmT_w  = (short*)ws; ws += NLAYER * HH * HH / 2;
    short* MmT_w  = (short*)ws; ws += NLAYER * HH * HH / 2;
    short* WT4_w  = (short*)ws; ws += NLAYER * 4 * HH * HH / 2;
    short* WT3_w  = (short*)ws; ws += NLAYER * 3 * HH * HH / 2;

    const int NPREP = BB + NLAYER * (HH + 1) + NLAYER * 7;
    k_prep<<<NPREP, 256, 0, stream>>>(hist, mask, Wp, bp, We2, be2, Wa1, ba1, Wm1, bm1,
                                      Wo1, Wm2, Wo2, ts_w, h_w, AmT_w, MmT_w, ca_w, cm_w, WT4_w, WT3_w);
    k_pre<<<BB * LL / 16, 512, 0, stream>>>(h_w, WT4_w, ca_w, cm_w, ba_w, da_w, bm_w, oa_w, 0);
    for (int l = 0; l < NLAYER; l++) {
        k_attn<<<BB * LL, 512, 0, stream>>>(hist, mask, ts_w, ba_w, bm_w, da_w, AmT_w, MmT_w,
                                            wa2, ba2, We1, be1, v_w, l);
        int do_pre = (l < NLAYER - 1) ? 1 : 0;
        float* hcopy = (l == NLAYER - 1) ? (out + BB * FUT * MDIM) : nullptr;
        k_post<<<BB * LL / 16, 512, 0, stream>>>(v_w, oa_w, h_w, mask, WT3_w, bm2, bo1, bo2,
                                                 ln_g, ln_b, h_w, hcopy, l,
                                                 do_pre, WT4_w, ca_w, cm_w, ba_w, da_w, bm_w, oa_w,
                                                 hist, hg, hb, Wh1, bh1, Wh2, bh2, out);
    }
}

// Round 12
// 247.276 us; speedup vs baseline: 1.0456x; 1.0351x over previous
//
#include <hip/hip_runtime.h>
#include <math.h>

#define BB 16
#define LL 128
#define D_IN 8
#define HH 128
#define NLAYER 2
#define FUT 12
#define MDIM 2

typedef __attribute__((ext_vector_type(8))) __bf16 bf16x8;
typedef __attribute__((ext_vector_type(8))) short short8v;
typedef __attribute__((ext_vector_type(4))) short short4v;
typedef __attribute__((ext_vector_type(4))) float f32x4;

#define MFMA_B16(A, B, C) __builtin_amdgcn_mfma_f32_16x16x32_bf16(A, B, C, 0, 0, 0)

static __device__ __forceinline__ short f2bf(float f) {
    union { float f; unsigned u; } v; v.f = f;
    unsigned r = v.u + 0x7FFFu + ((v.u >> 16) & 1u);
    return (short)(r >> 16);
}

static __device__ __forceinline__ float tanh_fast(float x) {
    float e = __expf(2.f * x);
    return 1.f - 2.f / (e + 1.f);
}

// ---------------- merged prep: ts+h0 (LDS-staged) | compose (split-K) | tiled weight transpose ----------------
__global__ __launch_bounds__(256) void k_prep(const float* __restrict__ hist, const float* __restrict__ mask,
                                              const float* __restrict__ Wp, const float* __restrict__ bp,
                                              const float* __restrict__ We2, const float* __restrict__ be2,
                                              const float* __restrict__ Wa1, const float* __restrict__ ba1,
                                              const float* __restrict__ Wm1, const float* __restrict__ bm1,
                                              const float* __restrict__ Wo1, const float* __restrict__ Wm2,
                                              const float* __restrict__ Wo2,
                                              float* __restrict__ ts, float* __restrict__ h,
                                              short* __restrict__ AmT, short* __restrict__ MmT,
                                              float* __restrict__ ca, float* __restrict__ cm,
                                              short* __restrict__ WT4, short* __restrict__ WT3) {
    __shared__ float row[HH];
    __shared__ float pa[256], pm[256];
    __shared__ float hrow[LL * D_IN];
    __shared__ float tile[64][65];
    const int bid = blockIdx.x, tid = threadIdx.x;
    const int NC = NLAYER * (HH + 1);
    if (bid < BB) {
        int b = bid;
#pragma unroll
        for (int e = 0; e < 4; e++) hrow[e * 256 + tid] = hist[(size_t)b * LL * D_IN + e * 256 + tid];
        if (tid < LL) pa[tid] = mask[b * LL + tid];
        __syncthreads();
        if (tid < LL) row[tid] = fmaxf(hrow[tid * D_IN + 5], 0.f);
        __syncthreads();
        for (int d = 1; d < LL; d <<= 1) {
            float add = (tid < LL && tid >= d) ? row[tid - d] : 0.f;
            __syncthreads();
            if (tid < LL) row[tid] += add;
            __syncthreads();
        }
        if (tid < LL) ts[b * LL + tid] = row[tid];
        int k = tid & (HH - 1);
        float wp_r[D_IN];
#pragma unroll
        for (int f = 0; f < D_IN; f++) wp_r[f] = Wp[f * HH + k];
        float bpk = bp[k];
        int jbase = tid >> 7;
        for (int e = 0; e < 64; e++) {
            int j = e * 2 + jbase;
            const float* hr = &hrow[j * D_IN];
            float acc = bpk;
#pragma unroll
            for (int f = 0; f < D_IN; f++) acc += hr[f] * wp_r[f];
            h[(size_t)(b * LL + j) * HH + k] = acc * (pa[j] > 0.f ? 1.f : 0.f);
        }
    } else if (bid < BB + NC) {
        int cb = bid - BB;
        int l = cb / (HH + 1);
        int p = cb % (HH + 1);
        const float* WaE = Wa1 + (size_t)(l * 3 * HH + 2 * HH) * HH;
        const float* WmE = Wm1 + (size_t)(l * 2 * HH + HH) * HH;
        int q = tid & 127, kh = tid >> 7;
        if (tid < HH) row[tid] = (p < HH) ? We2[(size_t)(l * HH + p) * HH + tid] : be2[l * HH + tid];
        __syncthreads();
        float a = 0.f, m = 0.f;
        int kbase = kh * 64;
#pragma unroll 4
        for (int k = 0; k < 64; k++) {
            float w = row[kbase + k];
            a += w * WaE[(size_t)(kbase + k) * HH + q];
            m += w * WmE[(size_t)(kbase + k) * HH + q];
        }
        pa[tid] = a;
        pm[tid] = m;
        __syncthreads();
        if (tid < HH) {
            a = pa[tid] + pa[128 + tid];
            m = pm[tid] + pm[128 + tid];
            if (p < HH) {
                AmT[(size_t)l * HH * HH + tid * HH + p] = f2bf(a);
                MmT[(size_t)l * HH * HH + tid * HH + p] = f2bf(m);
            } else {
                ca[l * HH + tid] = a + ba1[l * HH + tid];
                cm[l * HH + tid] = m + bm1[l * HH + tid];
            }
        }
    } else {
        int m7 = bid - BB - NC;
        int l = m7 / 7, m = m7 % 7;
        const float* src;
        switch (m) {
            case 0: src = Wa1 + (size_t)(l * 3 * HH) * HH; break;
            case 1: src = Wa1 + (size_t)(l * 3 * HH + HH) * HH; break;
            case 2: src = Wm1 + (size_t)(l * 2 * HH) * HH; break;
            case 3: src = Wo1 + (size_t)(l * 2 * HH) * HH; break;
            case 4: src = Wm2 + (size_t)l * HH * HH; break;
            case 5: src = Wo1 + (size_t)(l * 2 * HH + HH) * HH; break;
            default: src = Wo2 + (size_t)l * HH * HH; break;
        }
        short* dst = (m < 4) ? (WT4 + (size_t)(l * 4 + m) * HH * HH)
                             : (WT3 + (size_t)(l * 3 + (m - 4)) * HH * HH);
        // tiled transpose: coalesced reads AND coalesced bf16 writes, 64x65 LDS tile
        const int cl = tid & 63, rq = tid >> 6;   // cl: inner col, rq: 0..3 row-quarter
#pragma unroll
        for (int tt = 0; tt < 4; tt++) {
            int ti = tt >> 1, tj = tt & 1;
#pragma unroll 4
            for (int e = 0; e < 16; e++) {
                int r = rq * 16 + e;
                tile[r][cl] = src[(size_t)(ti * 64 + r) * HH + tj * 64 + cl];
            }
            __syncthreads();
#pragma unroll 4
            for (int e = 0; e < 16; e++) {
                int r2 = rq * 16 + e;
                dst[(size_t)(tj * 64 + r2) * HH + ti * 64 + cl] = f2bf(tile[cl][r2]);
            }
            __syncthreads();
        }
    }
}

// ---------------- batched pre-projections, 128 blocks x 512 threads ----------------
__global__ __launch_bounds__(512) void k_pre(const float* __restrict__ h, const short* __restrict__ WT4,
                                             const float* __restrict__ ca, const float* __restrict__ cm,
                                             float* __restrict__ base_a, float* __restrict__ da,
                                             float* __restrict__ base_m, float* __restrict__ oa, int l) {
    __shared__ __align__(16) short hA[16][136];
    const int tid = threadIdx.x, lane = tid & 63, wv = tid >> 6;
    const int lo = lane & 15, g4 = lane >> 4;
    const int r0 = blockIdx.x * 16;
    const int mat = wv >> 1, colh = wv & 1;

    const short* Wl = WT4 + (size_t)(l * 4 + mat) * HH * HH;
    bf16x8 Bf[4][4];
#pragma unroll
    for (int t = 0; t < 4; t++) {
        int col = (colh * 4 + t) * 16 + lo;
#pragma unroll
        for (int ks = 0; ks < 4; ks++)
            Bf[t][ks] = *(const bf16x8*)(Wl + (size_t)col * HH + ks * 32 + g4 * 8);
    }

    {
        int row = tid >> 5, cc = (tid & 31) * 4;
        const float* hr = h + (size_t)(r0 + row) * HH + cc;
        short4v pk;
#pragma unroll
        for (int e = 0; e < 4; e++) pk[e] = f2bf(hr[e]);
        *(short4v*)&hA[row][cc] = pk;
    }
    __syncthreads();
    bf16x8 af[4];
#pragma unroll
    for (int ks = 0; ks < 4; ks++)
        af[ks] = *(const bf16x8*)&hA[lo][ks * 32 + g4 * 8];
    float* dst;
    const float* bias = nullptr;
    if (mat == 0) { dst = base_a; bias = ca + l * HH; }
    else if (mat == 1) dst = da;
    else if (mat == 2) { dst = base_m; bias = cm + l * HH; }
    else dst = oa;
#pragma unroll
    for (int t = 0; t < 4; t++) {
        int col = (colh * 4 + t) * 16 + lo;
        f32x4 acc = (f32x4){0.f, 0.f, 0.f, 0.f};
#pragma unroll
        for (int ks = 0; ks < 4; ks++) acc = MFMA_B16(af[ks], Bf[t][ks], acc);
        float bv = bias ? bias[col] : 0.f;
#pragma unroll
        for (int rg = 0; rg < 4; rg++)
            dst[(size_t)(r0 + g4 * 4 + rg) * HH + col] = acc[rg] + bv;
    }
}

// ---------------- attention core: 512 threads, C[k][j], packed-fp32 t-compute ----------------
__global__ __launch_bounds__(512) void k_attn(
    const float* __restrict__ hist, const float* __restrict__ mask, const float* __restrict__ ts,
    const float* __restrict__ base_a_g, const float* __restrict__ base_m_g, const float* __restrict__ da,
    const short* __restrict__ AmT, const short* __restrict__ MmT,
    const float* __restrict__ wa2, const float* __restrict__ ba2,
    const float* __restrict__ We1, const float* __restrict__ be1,
    float* __restrict__ v_out, int l) {
    __shared__ __align__(16) short t_lds[LL][LL];    // 32768 B, XOR-swizzled
    __shared__ __align__(16) float bufA[1024];
    __shared__ float w_lds[LL];
    __shared__ float val_s[LL];

    const int tid = threadIdx.x;
    const int lane = tid & 63;
    const int wv = tid >> 6;
    const int lo = lane & 15, g4 = lane >> 4;
    const int kq = wv * 16 + g4 * 4;
    const int bi = blockIdx.x, b = bi >> 7, i = bi & (LL - 1);

    const f32x4 ba4 = *(const f32x4*)(base_a_g + (size_t)bi * HH + kq);
    const f32x4 bm4 = *(const f32x4*)(base_m_g + (size_t)bi * HH + kq);
    const f32x4 wa4 = *(const f32x4*)(wa2 + l * HH + kq);
    const float ba2l = ba2[l];

    bf16x8 Bf[4];
#pragma unroll
    for (int ks = 0; ks < 4; ks++)
        Bf[ks] = *(const bf16x8*)(AmT + (size_t)l * HH * HH + (size_t)(wv * 16 + lo) * HH + ks * 32 + g4 * 8);

    {
        const float* We1l = We1 + l * 4 * HH;
        const float* be1l = be1 + l * HH;
        if (tid < 256) bufA[tid] = We1l[tid];
        else if (tid < 384) bufA[tid] = be1l[tid - 256];
        else bufA[tid] = be1l[tid - 384] + We1l[256 + (tid - 384)];
        if (tid < 128) {
            bufA[512 + tid] = We1l[384 + tid];
            val_s[tid] = mask[b * LL + tid];
        }
    }
    __syncthreads();

    {
        int jj = tid & (LL - 1);
        int q4 = tid >> 7;
        const float* hri = hist + (size_t)(b * LL + i) * D_IN;
        const float* hrj = hist + (size_t)(b * LL + jj) * D_IN;
        float dlat = hri[0] - hrj[0], dlon = hri[1] - hrj[1];
        float ea = sqrtf(dlat * dlat + dlon * dlon + 1e-8f);
        float eb = fabsf(ts[b * LL + i] - ts[b * LL + jj]) * (1.f / 300.f);
        const float* basep = bufA + ((hri[6] == hrj[6]) ? 384 : 256);
        char* trow = (char*)t_lds + jj * 256;
        int swz = (jj & 7) << 4;
        bool diag = (jj == i);
#pragma unroll
        for (int pass = 0; pass < 4; pass++) {
            int r0c = (q4 + pass * 4) * 8;
            f32x4 v0, v1;
            {
                f32x4 wa0 = *(const f32x4*)&bufA[r0c];
                f32x4 wb0 = *(const f32x4*)&bufA[128 + r0c];
                f32x4 bs0 = *(const f32x4*)&basep[r0c];
                v0 = wa0 * ea + wb0 * eb + bs0;
                f32x4 wa1 = *(const f32x4*)&bufA[r0c + 4];
                f32x4 wb1 = *(const f32x4*)&bufA[128 + r0c + 4];
                f32x4 bs1 = *(const f32x4*)&basep[r0c + 4];
                v1 = wa1 * ea + wb1 * eb + bs1;
            }
            if (diag) {
                v0 += *(const f32x4*)&bufA[512 + r0c];
                v1 += *(const f32x4*)&bufA[512 + r0c + 4];
            }
            bf16x8 pkb;
#pragma unroll
            for (int e = 0; e < 4; e++) {
                pkb[e] = (__bf16)fmaxf(v0[e], 0.f);
                pkb[4 + e] = (__bf16)fmaxf(v1[e], 0.f);
            }
            *(bf16x8*)(trow + ((r0c * 2) ^ swz)) = pkb;
        }
    }
    __syncthreads();

    const float* da_b = da + (size_t)(b * LL) * HH;
    const int rswz = (lo & 7) << 4;

#pragma unroll
    for (int jh = 0; jh < 2; jh++) {
        f32x4 acc[4];
#pragma unroll
        for (int m = 0; m < 4; m++) {
            int j0 = (jh * 4 + m) * 16 + lo;
            acc[m] = *(const f32x4*)(da_b + (size_t)j0 * HH + kq);
        }
#pragma unroll
        for (int ks = 0; ks < 4; ks++) {
            bf16x8 tf[4];
#pragma unroll
            for (int m = 0; m < 4; m++) {
                int row = (jh * 4 + m) * 16 + lo;
                tf[m] = *(const bf16x8*)((const char*)t_lds + row * 256 + ((ks * 64 + g4 * 16) ^ rswz));
            }
#pragma unroll
            for (int m = 0; m < 4; m++) acc[m] = MFMA_B16(Bf[ks], tf[m], acc[m]);
        }
#pragma unroll
        for (int m = 0; m < 4; m++) {
            f32x4 s = acc[m] + ba4;
            float p0 = tanh_fast(s[0]) * wa4[0];
            float p1 = tanh_fast(s[1]) * wa4[1];
            float p2 = tanh_fast(s[2]) * wa4[2];
            float p3 = tanh_fast(s[3]) * wa4[3];
            float p = (p0 + p1) + (p2 + p3);
            p += __shfl_xor(p, 16);
            p += __shfl_xor(p, 32);
            if (g4 == 0) bufA[wv * LL + (jh * 4 + m) * 16 + lo] = p;
        }
    }

#pragma unroll
    for (int ks = 0; ks < 4; ks++)
        Bf[ks] = *(const bf16x8*)(MmT + (size_t)l * HH * HH + (size_t)(wv * 16 + lo) * HH + ks * 32 + g4 * 8);
    __syncthreads();

    {
        const float inv = 0.08838834764831845f;
        float vi = val_s[i];
        float a0 = ba2l, a1 = ba2l;
#pragma unroll
        for (int w = 0; w < 8; w++) {
            a0 += bufA[w * LL + lane];
            a1 += bufA[w * LL + 64 + lane];
        }
        a0 *= inv; a1 *= inv;
        if (!(val_s[lane] > 0.f) || !(vi > 0.f)) a0 = -1e9f;
        if (!(val_s[64 + lane] > 0.f) || !(vi > 0.f)) a1 = -1e9f;
        float m = fmaxf(a0, a1);
#pragma unroll
        for (int d = 1; d < 64; d <<= 1) m = fmaxf(m, __shfl_xor(m, d));
        float e0 = __expf(a0 - m), e1 = __expf(a1 - m);
        float s = e0 + e1;
#pragma unroll
        for (int d = 1; d < 64; d <<= 1) s += __shfl_xor(s, d);
        float rs = 1.f / s;
        w_lds[lane] = e0 * rs;
        w_lds[64 + lane] = e1 * rs;
    }

    f32x4 macv = (f32x4){0.f, 0.f, 0.f, 0.f};
#pragma unroll
    for (int jh = 0; jh < 2; jh++) {
        f32x4 acc[4];
#pragma unroll
        for (int m = 0; m < 4; m++) acc[m] = (f32x4){0.f, 0.f, 0.f, 0.f};
#pragma unroll
        for (int ks = 0; ks < 4; ks++) {
            bf16x8 tf[4];
#pragma unroll
            for (int m = 0; m < 4; m++) {
                int row = (jh * 4 + m) * 16 + lo;
                tf[m] = *(const bf16x8*)((const char*)t_lds + row * 256 + ((ks * 64 + g4 * 16) ^ rswz));
            }
#pragma unroll
            for (int m = 0; m < 4; m++) acc[m] = MFMA_B16(Bf[ks], tf[m], acc[m]);
        }
#pragma unroll
        for (int m = 0; m < 4; m++) {
            float wj = w_lds[(jh * 4 + m) * 16 + lo];
            f32x4 mm = acc[m] + bm4;
#pragma unroll
            for (int rg = 0; rg < 4; rg++) mm[rg] = fmaxf(mm[rg], 0.f);
            macv += mm * wj;
        }
    }
#pragma unroll
    for (int rg = 0; rg < 4; rg++) {
        macv[rg] += __shfl_xor(macv[rg], 1);
        macv[rg] += __shfl_xor(macv[rg], 2);
        macv[rg] += __shfl_xor(macv[rg], 4);
        macv[rg] += __shfl_xor(macv[rg], 8);
    }
    if (lo == 0) *(f32x4*)(v_out + (size_t)bi * HH + kq) = macv;
}

// ---------------- batched post, 128 blocks x 512 threads: wave owns 16 cols ----------------
__global__ __launch_bounds__(512) void k_post(
    const float* __restrict__ v, const float* __restrict__ oa_in, const float* __restrict__ h,
    const float* __restrict__ mask, const short* __restrict__ WT3,
    const float* __restrict__ bm2, const float* __restrict__ bo1, const float* __restrict__ bo2,
    const float* __restrict__ ln_g, const float* __restrict__ ln_b,
    float* __restrict__ hout, float* __restrict__ hcopy, int l,
    int do_pre, const short* __restrict__ WT4, const float* __restrict__ ca, const float* __restrict__ cm,
    float* __restrict__ base_a, float* __restrict__ da, float* __restrict__ base_m, float* __restrict__ oa_out,
    const float* __restrict__ hist, const float* __restrict__ hg, const float* __restrict__ hb,
    const float* __restrict__ Wh1, const float* __restrict__ bh1,
    const float* __restrict__ Wh2, const float* __restrict__ bh2, float* __restrict__ dec_out) {
    __shared__ __align__(16) short xA[16][136];
    __shared__ __align__(16) short iA[16][136];
    __shared__ float red[2][8][16];
    __shared__ float ln_row[HH];
    __shared__ float dec_x[D_IN + HH];
    const int tid = threadIdx.x, lane = tid & 63, wv = tid >> 6;
    const int lo = lane & 15, g4 = lane >> 4;
    const int r0 = blockIdx.x * 16;
    const int c = wv * 16 + lo;

    bf16x8 BfA[4], BfB[4], BfC[4];
    {
        const short* WA = WT3 + (size_t)(l * 3 + 0) * HH * HH;
        const short* WB = WT3 + (size_t)(l * 3 + 1) * HH * HH;
        const short* WC = WT3 + (size_t)(l * 3 + 2) * HH * HH;
#pragma unroll
        for (int ks = 0; ks < 4; ks++) {
            BfA[ks] = *(const bf16x8*)(WA + (size_t)c * HH + ks * 32 + g4 * 8);
            BfB[ks] = *(const bf16x8*)(WB + (size_t)c * HH + ks * 32 + g4 * 8);
            BfC[ks] = *(const bf16x8*)(WC + (size_t)c * HH + ks * 32 + g4 * 8);
        }
    }

    float oaR[4], hR[4], vmR[4];
    const float bm2R = bm2[l * HH + c], bo1R = bo1[l * HH + c], bo2R = bo2[l * HH + c];
    const float gR = ln_g[l * HH + c], bR = ln_b[l * HH + c];
#pragma unroll
    for (int rg = 0; rg < 4; rg++) {
        int r = r0 + g4 * 4 + rg;
        vmR[rg] = mask[r];
        oaR[rg] = oa_in[(size_t)r * HH + c];
        hR[rg] = h[(size_t)r * HH + c];
    }

    int lastRow = -1;
    if (hcopy) {
        float mv = (tid < LL) ? mask[(r0 >> 7) * LL + tid] : 0.f;
#pragma unroll
        for (int d = 1; d < 64; d <<= 1) mv += __shfl_xor(mv, d);
        if (lane == 0) red[0][wv][0] = mv;
    }

    {
        int row = tid >> 5, cc = (tid & 31) * 4;
        const float* vr = v + (size_t)(r0 + row) * HH + cc;
        short4v pk;
#pragma unroll
        for (int e = 0; e < 4; e++) pk[e] = f2bf(vr[e]);
        *(short4v*)&xA[row][cc] = pk;
    }
    __syncthreads();

    if (hcopy) {
        float vcs = 0.f;
#pragma unroll
        for (int w = 0; w < 8; w++) vcs += red[0][w][0];
        int vc = (int)vcs;
        vc = min(max(vc, 1), LL);
        lastRow = (r0 & ~(LL - 1)) + vc - 1;
    }

    bf16x8 af[4];
    f32x4 acc;

#pragma unroll
    for (int ks = 0; ks < 4; ks++) af[ks] = *(const bf16x8*)&xA[lo][ks * 32 + g4 * 8];
    acc = (f32x4){0.f, 0.f, 0.f, 0.f};
#pragma unroll
    for (int ks = 0; ks < 4; ks++) acc = MFMA_B16(af[ks], BfA[ks], acc);
#pragma unroll
    for (int rg = 0; rg < 4; rg++) iA[g4 * 4 + rg][c] = f2bf(acc[rg] + bm2R);
    __syncthreads();

#pragma unroll
    for (int ks = 0; ks < 4; ks++) af[ks] = *(const bf16x8*)&iA[lo][ks * 32 + g4 * 8];
    acc = (f32x4){0.f, 0.f, 0.f, 0.f};
#pragma unroll
    for (int ks = 0; ks < 4; ks++) acc = MFMA_B16(af[ks], BfB[ks], acc);
#pragma unroll
    for (int rg = 0; rg < 4; rg++)
        xA[g4 * 4 + rg][c] = f2bf(fmaxf(acc[rg] + oaR[rg] + bo1R, 0.f));
    __syncthreads();

    float y[4];
#pragma unroll
    for (int ks = 0; ks < 4; ks++) af[ks] = *(const bf16x8*)&xA[lo][ks * 32 + g4 * 8];
    acc = (f32x4){0.f, 0.f, 0.f, 0.f};
#pragma unroll
    for (int ks = 0; ks < 4; ks++) acc = MFMA_B16(af[ks], BfC[ks], acc);
#pragma unroll
    for (int rg = 0; rg < 4; rg++) y[rg] = acc[rg] + bo2R + hR[rg];

#pragma unroll
    for (int rg = 0; rg < 4; rg++) {
        float s = y[rg];
        float s2 = y[rg] * y[rg];
#pragma unroll
        for (int d = 1; d < 16; d <<= 1) { s += __shfl_xor(s, d); s2 += __shfl_xor(s2, d); }
        if (lo == 0) {
            red[0][wv][g4 * 4 + rg] = s;
            red[1][wv][g4 * 4 + rg] = s2;
        }
    }
    __syncthreads();
#pragma unroll
    for (int rg = 0; rg < 4; rg++) {
        int rl = g4 * 4 + rg;
        float mu = 0.f, ex2 = 0.f;
#pragma unroll
        for (int w = 0; w < 8; w++) { mu += red[0][w][rl]; ex2 += red[1][w][rl]; }
        mu *= (1.f / HH);
        ex2 *= (1.f / HH);
        float var = ex2 - mu * mu;
        float rs = rsqrtf(var + 1e-5f);
        float vm = vmR[rg] > 0.f ? 1.f : 0.f;
        int r = r0 + rl;
        float hv = ((y[rg] - mu) * rs * gR + bR) * vm;
        hout[(size_t)r * HH + c] = hv;
        if (hcopy) hcopy[(size_t)r * HH + c] = hv;
        if (do_pre) xA[rl][c] = f2bf(hv);
        if (lastRow >= 0 && r == lastRow) ln_row[c] = hv;
    }

    if (do_pre) {
        int ln = l + 1;
        int mat = wv >> 1, colh = wv & 1;
        const short* Wl = WT4 + (size_t)(ln * 4 + mat) * HH * HH;
        bf16x8 Bf2[4][4];
#pragma unroll
        for (int t = 0; t < 4; t++) {
            int col2 = (colh * 4 + t) * 16 + lo;
#pragma unroll
            for (int ks = 0; ks < 4; ks++)
                Bf2[t][ks] = *(const bf16x8*)(Wl + (size_t)col2 * HH + ks * 32 + g4 * 8);
        }
        __syncthreads();
        bf16x8 af2[4];
#pragma unroll
        for (int ks = 0; ks < 4; ks++) af2[ks] = *(const bf16x8*)&xA[lo][ks * 32 + g4 * 8];
        float* dst;
        const float* bias = nullptr;
        if (mat == 0) { dst = base_a; bias = ca + ln * HH; }
        else if (mat == 1) dst = da;
        else if (mat == 2) { dst = base_m; bias = cm + ln * HH; }
        else dst = oa_out;
#pragma unroll
        for (int t = 0; t < 4; t++) {
            int col2 = (colh * 4 + t) * 16 + lo;
            f32x4 a2 = (f32x4){0.f, 0.f, 0.f, 0.f};
#pragma unroll
            for (int ks = 0; ks < 4; ks++) a2 = MFMA_B16(af2[ks], Bf2[t][ks], a2);
            float bv = bias ? bias[col2] : 0.f;
#pragma unroll
            for (int rg = 0; rg < 4; rg++)
                dst[(size_t)(r0 + g4 * 4 + rg) * HH + col2] = a2[rg] + bv;
        }
    }

    if (hcopy && lastRow >= r0 && lastRow < r0 + 16) {
        const int N = D_IN + HH;  // 136
        __syncthreads();
        if (tid < D_IN) dec_x[tid] = hist[(size_t)lastRow * D_IN + tid];
        if (tid < HH) dec_x[D_IN + tid] = ln_row[tid];
        __syncthreads();
        float px = (tid < N) ? dec_x[tid] : 0.f;
        float px2 = px * px;
#pragma unroll
        for (int d = 1; d < 64; d <<= 1) { px += __shfl_xor(px, d); px2 += __shfl_xor(px2, d); }
        if (lane == 0) { red[0][wv][0] = px; red[1][wv][0] = px2; }
        __syncthreads();
        float mu = 0.f, ex2 = 0.f;
#pragma unroll
        for (int w = 0; w < 8; w++) { mu += red[0][w][0]; ex2 += red[1][w][0]; }
        mu /= (float)N;
        ex2 /= (float)N;
        float var = ex2 - mu * mu;
        float rs = rsqrtf(var + 1e-5f);
        if (tid < N) dec_x[tid] = (dec_x[tid] - mu) * rs * hg[tid] + hb[tid];
        __syncthreads();
        if (tid < HH) {
            float a = bh1[tid];
            for (int f = 0; f < N; f++) a += dec_x[f] * Wh1[(size_t)f * HH + tid];
            ln_row[tid] = fmaxf(a, 0.f);
        }
        __syncthreads();
        if (tid < FUT * MDIM) {
            float o = bh2[tid];
            for (int k = 0; k < HH; k++) o += ln_row[k] * Wh2[(size_t)k * FUT * MDIM + tid];
            if (isnan(o)) o = 0.f;
            else if (isinf(o)) o = (o > 0.f) ? 1e4f : -1e4f;
            dec_out[(r0 >> 7) * FUT * MDIM + tid] = o;
        }
    }
}

extern "C" void kernel_launch(void* const* d_in, const int* in_sizes, int n_in,
                              void* d_out, int out_size, void* d_ws, size_t ws_size,
                              hipStream_t stream) {
    const float* hist = (const float*)d_in[0];
    const float* mask = (const float*)d_in[1];
    const float* Wp  = (const float*)d_in[2];
    const float* bp  = (const float*)d_in[3];
    const float* We1 = (const float*)d_in[4];
    const float* be1 = (const float*)d_in[5];
    const float* We2 = (const float*)d_in[6];
    const float* be2 = (const float*)d_in[7];
    const float* Wa1 = (const float*)d_in[8];
    const float* ba1 = (const float*)d_in[9];
    const float* wa2 = (const float*)d_in[10];
    const float* ba2 = (const float*)d_in[11];
    const float* Wm1 = (const float*)d_in[12];
    const float* bm1 = (const float*)d_in[13];
    const float* Wm2 = (const float*)d_in[14];
    const float* bm2 = (const float*)d_in[15];
    const float* Wo1 = (const float*)d_in[16];
    const float* bo1 = (const float*)d_in[17];
    const float* Wo2 = (const float*)d_in[18];
    const float* bo2 = (const float*)d_in[19];
    const float* ln_g = (const float*)d_in[20];
    const float* ln_b = (const float*)d_in[21];
    const float* hg  = (const float*)d_in[22];
    const float* hb  = (const float*)d_in[23];
    const float* Wh1 = (const float*)d_in[24];
    const float* bh1 = (const float*)d_in[25];
    const float* Wh2 = (const float*)d_in[26];
    const float* bh2 = (const float*)d_in[27];
    float* out = (float*)d_out;

    float* ws = (float*)d_ws;
    float* ts_w   = ws; ws += BB * LL;
    float* h_w    = ws; ws += BB * LL * HH;
    float* da_w   = ws; ws += BB * LL * HH;
    float* ba_w   = ws; ws += BB * LL * HH;   // base_a
    float* bm_w   = ws; ws += BB * LL * HH;   // base_m
    float* oa_w   = ws; ws += BB * LL * HH;
    float* v_w    = ws; ws += BB * LL * HH;
    float* ca_w   = ws; ws += NLAYER * HH;
    float* cm_w   = ws; ws += NLAYER * HH;
    short* AmT_w  = (short*)ws; ws += NLAYER * HH * HH / 2;
    short* MmT_w  = (short*)ws; ws += NLAYER * HH * HH / 2;
    short* WT4_w  = (short*)ws; ws += NLAYER * 4 * HH * HH / 2;
    short* WT3_w  = (short*)ws; ws += NLAYER * 3 * HH * HH / 2;

    const int NPREP = BB + NLAYER * (HH + 1) + NLAYER * 7;
    k_prep<<<NPREP, 256, 0, stream>>>(hist, mask, Wp, bp, We2, be2, Wa1, ba1, Wm1, bm1,
                                      Wo1, Wm2, Wo2, ts_w, h_w, AmT_w, MmT_w, ca_w, cm_w, WT4_w, WT3_w);
    k_pre<<<BB * LL / 16, 512, 0, stream>>>(h_w, WT4_w, ca_w, cm_w, ba_w, da_w, bm_w, oa_w, 0);
    for (int l = 0; l < NLAYER; l++) {
        k_attn<<<BB * LL, 512, 0, stream>>>(hist, mask, ts_w, ba_w, bm_w, da_w, AmT_w, MmT_w,
                                            wa2, ba2, We1, be1, v_w, l);
        int do_pre = (l < NLAYER - 1) ? 1 : 0;
        float* hcopy = (l == NLAYER - 1) ? (out + BB * FUT * MDIM) : nullptr;
        k_post<<<BB * LL / 16, 512, 0, stream>>>(v_w, oa_w, h_w, mask, WT3_w, bm2, bo1, bo2,
                                                 ln_g, ln_b, h_w, hcopy, l,
                                                 do_pre, WT4_w, ca_w, cm_w, ba_w, da_w, bm_w, oa_w,
                                                 hist, hg, hb, Wh1, bh1, Wh2, bh2, out);
    }
}